// Round 4
// baseline (582.040 us; speedup 1.0000x reference)
//
#include <hip/hip_runtime.h>
#include <hip/hip_bf16.h>

typedef unsigned short u16;
typedef unsigned int   u32;

typedef __bf16 bf16x8 __attribute__((ext_vector_type(8)));
typedef float  f32x4  __attribute__((ext_vector_type(4)));

// ---------- helpers ----------
__device__ __forceinline__ u16 f2bf(float f) {  // RNE
  u32 u = __float_as_uint(f);
  u += 0x7fffu + ((u >> 16) & 1u);
  return (u16)(u >> 16);
}
__device__ __forceinline__ u32 pack2(float a, float b) {
  return (u32)f2bf(a) | ((u32)f2bf(b) << 16);
}
__device__ __forceinline__ void gld16(const void* g, void* l) {
  __builtin_amdgcn_global_load_lds(
      (const __attribute__((address_space(1))) unsigned int*)g,
      (__attribute__((address_space(3))) unsigned int*)l, 16, 0, 0);
}

// Problem constants
#define TOK_M   78848   // B*N = 8*9856
#define DIM     256
#define NWIN    1024    // 8 * 8 * 16
#define WINL    77      // 7*11

// ---------- weight conversion ----------
// Image layout (qkv, fc1): [panel][kt][nf][lane][8] — 16B per lane slot.
//   col = panel*128 + nf*16 + (lane&15), k = kt*32 + (lane>>4)*8
// Plain layout (wout, fc2): row-major [N][K] bf16.
template<int K, int NF>
__device__ __forceinline__ void cvt_chunk(const float* __restrict__ src,
                                          u16* __restrict__ dst, int rel)
{
  constexpr int KT = K / 32;
  constexpr int PN = NF * 16;
  const int lane  = rel & 63;
  const int g     = rel >> 6;
  const int nf    = g % NF;
  const int kt    = (g / NF) % KT;
  const int panel = g / (NF * KT);
  const int col   = panel * PN + nf * 16 + (lane & 15);
  const int k0    = kt * 32 + (lane >> 4) * 8;
  const float4 a = *(const float4*)(src + (size_t)col * K + k0);
  const float4 b = *(const float4*)(src + (size_t)col * K + k0 + 4);
  uint4 o;
  o.x = pack2(a.x, a.y); o.y = pack2(a.z, a.w);
  o.z = pack2(b.x, b.y); o.w = pack2(b.z, b.w);
  *(uint4*)(dst + (size_t)rel * 8) = o;
}
__device__ __forceinline__ void cvt_plain(const float* __restrict__ src,
                                          u16* __restrict__ dst, int rel)
{
  const int i = rel * 8;
  const float4 a = *(const float4*)(src + i);
  const float4 b = *(const float4*)(src + i + 4);
  uint4 o;
  o.x = pack2(a.x, a.y); o.y = pack2(a.z, a.w);
  o.z = pack2(b.x, b.y); o.w = pack2(b.z, b.w);
  *(uint4*)(dst + i) = o;
}

__global__ __launch_bounds__(256)
void cvt_w(const float* __restrict__ wqkv, const float* __restrict__ wout,
           const float* __restrict__ w1, const float* __restrict__ w2,
           u16* __restrict__ out)
{
  const int c = blockIdx.x * 256 + threadIdx.x;   // [0, 65536) 16B chunks
  if      (c < 24576) cvt_chunk<256, 8>(wqkv, out,          c);          // qkv image 768x256
  else if (c < 32768) cvt_plain(wout, out + 196608, c - 24576);          // out plain 256x256
  else if (c < 49152) cvt_chunk<256, 8>(w1,   out + 262144, c - 32768);  // fc1 image 512x256
  else                cvt_plain(w2,   out + 393216, c - 49152);          // fc2 plain 256x512
}

// ---------- fused LayerNorm + GEMM, counted-vmcnt pipeline ----------
// Block: 64 natural-token rows, 4 waves (2x2). Phase 1: 16 row-loads issued
// up-front (16KB in flight/wave), LN per row, bf16 A-tile resident in LDS
// (32KB, XOR row-swizzled: col ^ (row&7)*8 -> <=2-way banks). Phase 2:
// NPAN*KT steps; B staged 2 steps ahead into 4 rotating 8KB buffers;
// s_waitcnt vmcnt(4) (NOT 0) + raw s_barrier per step -> loads stay in
// flight across barriers. PERM: window-permute rows on write (qkv).
template<int NPAN, int EPI, int OBF, int PERM>
__global__ __launch_bounds__(256, 2)
void lngemm(const float* __restrict__ X, const u16* __restrict__ Wimg,
            const float* __restrict__ lg, const float* __restrict__ lb,
            const float* __restrict__ bias, void* __restrict__ Cout)
{
  constexpr int K  = 256;
  constexpr int KT = K / 32;
  constexpr int N  = NPAN * 128;
  constexpr int NSTEP = NPAN * KT;
  __shared__ u16 At[64 * K];      // 32 KB resident A tile
  __shared__ u16 Bs[4][4096];     // 4 x 8 KB rotating B buffers

  const int tid  = threadIdx.x;
  const int wave = tid >> 6, lane = tid & 63;
  const int quad = lane >> 4, l16 = lane & 15;
  const int wy = wave >> 1, wx = wave & 1;
  const int rowbase = blockIdx.x * 64;

  // ---- phase 1: LN -> LDS A-tile (all 16 row-loads in flight first) ----
  {
    const float4 gg = *(const float4*)(lg + lane * 4);
    const float4 bb = *(const float4*)(lb + lane * 4);
    const int c = lane * 4;
    float4 xv[16];
#pragma unroll
    for (int r = 0; r < 16; ++r)
      xv[r] = *(const float4*)(X + (size_t)(rowbase + wave * 16 + r) * 256 + c);
#pragma unroll
    for (int r = 0; r < 16; ++r) {
      const int row = wave * 16 + r;
      const float4 v = xv[r];
      float s = v.x + v.y + v.z + v.w;
#pragma unroll
      for (int off = 32; off; off >>= 1) s += __shfl_xor(s, off);
      const float mu = s * (1.f / 256.f);
      const float dx = v.x - mu, dy = v.y - mu, dz = v.z - mu, dw = v.w - mu;
      float q = dx * dx + dy * dy + dz * dz + dw * dw;
#pragma unroll
      for (int off = 32; off; off >>= 1) q += __shfl_xor(q, off);
      const float rstd = rsqrtf(q * (1.f / 256.f) + 1e-5f);
      uint2 o;
      o.x = pack2(dx * rstd * gg.x + bb.x, dy * rstd * gg.y + bb.y);
      o.y = pack2(dz * rstd * gg.z + bb.z, dw * rstd * gg.w + bb.w);
      *(uint2*)(At + row * 256 + (c ^ ((row & 7) * 8))) = o;
    }
  }
  // prologue: stage steps 0,1
  gld16(Wimg + tid * 8,        Bs[0] + tid * 8);
  gld16(Wimg + 2048 + tid * 8, Bs[0] + 2048 + tid * 8);
  gld16(Wimg + 4096 + tid * 8,        Bs[1] + tid * 8);
  gld16(Wimg + 4096 + 2048 + tid * 8, Bs[1] + 2048 + tid * 8);

  // ---- phase 2: panels x K-steps ----
  int step = 0;
  for (int np = 0; np < NPAN; ++np) {
    f32x4 acc[2][4];
#pragma unroll
    for (int mi = 0; mi < 2; ++mi)
#pragma unroll
      for (int ni = 0; ni < 4; ++ni) {
        f32x4 z = {0.f, 0.f, 0.f, 0.f};
        acc[mi][ni] = z;
      }
#pragma unroll
    for (int kt = 0; kt < KT; ++kt, ++step) {
      {  // stage step+2 (clamped at tail so vmcnt accounting stays uniform)
        const int sn = (step + 2 < NSTEP) ? step + 2 : NSTEP - 1;
        const u16* src = Wimg + (size_t)sn * 4096;
        u16* dst = Bs[(step + 2) & 3];
        gld16(src + tid * 8,        dst + tid * 8);
        gld16(src + 2048 + tid * 8, dst + 2048 + tid * 8);
      }
      asm volatile("s_waitcnt vmcnt(4) lgkmcnt(0)" ::: "memory");
      __builtin_amdgcn_s_barrier();
      __builtin_amdgcn_sched_barrier(0);
      bf16x8 af[2], bv[4];
#pragma unroll
      for (int mi = 0; mi < 2; ++mi) {
        const int row = wy * 32 + mi * 16 + l16;
        af[mi] = *(const bf16x8*)(At + row * 256 +
                                  ((kt * 32 + quad * 8) ^ ((row & 7) * 8)));
      }
#pragma unroll
      for (int ni = 0; ni < 4; ++ni)
        bv[ni] = *(const bf16x8*)(Bs[step & 3] + ((wx * 4 + ni) * 64 + lane) * 8);
#pragma unroll
      for (int mi = 0; mi < 2; ++mi)
#pragma unroll
        for (int ni = 0; ni < 4; ++ni)
          acc[mi][ni] = __builtin_amdgcn_mfma_f32_16x16x32_bf16(
              af[mi], bv[ni], acc[mi][ni], 0, 0, 0);
    }
    // ---- epilogue for this panel ----
    const int col0 = np * 128 + wx * 64 + l16;
#pragma unroll
    for (int mi = 0; mi < 2; ++mi) {
      const int r = rowbase + wy * 32 + mi * 16 + quad * 4;
#pragma unroll
      for (int e = 0; e < 4; ++e) {
        const int gr = r + e;          // natural token index
        size_t orow = (size_t)gr;
        if (PERM) {
          const int b  = gr / 9856, n = gr - b * 9856;
          const int y  = n / 176,  xc = n - y * 176;
          const int ih = y / 7,    rr = y - ih * 7;
          const int iw = xc / 11,  cc = xc - iw * 11;
          orow = (size_t)(((b * 8 + ih) * 16 + iw)) * 77 + rr * 11 + cc;
        }
#pragma unroll
        for (int ni = 0; ni < 4; ++ni) {
          const int col = col0 + ni * 16;
          float v = acc[mi][ni][e] + bias[col];
          if (EPI == 2) v = 0.5f * v * (1.f + erff(v * 0.70710678118654752f));
          const size_t idx = orow * N + col;
          if (OBF) ((u16*)Cout)[idx] = f2bf(v);
          else     ((float*)Cout)[idx] = v;
        }
      }
    }
  }
}

// ---------- MFMA GEMM, counted-vmcnt pipeline ----------
// C = A(bf16)[M,K] @ W(bf16)[N,K]^T + bias (+epi). 4 rotating 16KB tile
// buffers (A+B), stage 2 steps ahead; s_waitcnt vmcnt(8) + raw s_barrier
// per step (loads span barriers). Swizzle p(r)=(r>>1)&3 -> <=2-way banks.
template<int EPI, int OBF>
__global__ __launch_bounds__(256, 2)
void gemm_mfma(const u16* __restrict__ A, const u16* __restrict__ W,
               const float* __restrict__ bias, const float* res,
               void* Cout, int N, int K)
{
  __shared__ u16 As[4][4096];
  __shared__ u16 Bs[4][4096];

  const int tid  = threadIdx.x;
  const int wave = tid >> 6, lane = tid & 63;
  const int wy = wave >> 1, wx = wave & 1;
  const int quad = lane >> 4, l16 = lane & 15;
  const int m0 = blockIdx.y * 128;
  const int n0 = blockIdx.x * 128;

  const int s0 = tid, s1 = tid + 256;
  const int r0 = s0 >> 2, r1 = s1 >> 2;
  const int kb0 = (s0 & 3) ^ ((r0 >> 1) & 3);
  const int kb1 = (s1 & 3) ^ ((r1 >> 1) & 3);
  const u16* Ag0 = A + (size_t)(m0 + r0) * K + kb0 * 8;
  const u16* Ag1 = A + (size_t)(m0 + r1) * K + kb1 * 8;
  const u16* Bg0 = W + (size_t)(n0 + r0) * K + kb0 * 8;
  const u16* Bg1 = W + (size_t)(n0 + r1) * K + kb1 * 8;

  const int kbs = quad ^ ((l16 >> 1) & 3);
  const int aoff = (wy * 64 + l16) * 32 + kbs * 8;
  const int boff = (wx * 64 + l16) * 32 + kbs * 8;

  f32x4 acc[4][4];
#pragma unroll
  for (int i = 0; i < 4; ++i)
#pragma unroll
    for (int j = 0; j < 4; ++j) {
      f32x4 z = {0.f, 0.f, 0.f, 0.f};
      acc[i][j] = z;
    }

  const int NT = K >> 5;
  auto stage = [&](int tile, int buf) {
    const int ko = tile * 32;
    gld16(Ag0 + ko, &As[buf][s0 * 8]);
    gld16(Ag1 + ko, &As[buf][s1 * 8]);
    gld16(Bg0 + ko, &Bs[buf][s0 * 8]);
    gld16(Bg1 + ko, &Bs[buf][s1 * 8]);
  };
  stage(0, 0);
  stage(1, 1);

  for (int t = 0; t < NT; ++t) {
    stage((t + 2 < NT) ? t + 2 : NT - 1, (t + 2) & 3);
    asm volatile("s_waitcnt vmcnt(8) lgkmcnt(0)" ::: "memory");
    __builtin_amdgcn_s_barrier();
    __builtin_amdgcn_sched_barrier(0);
    const u16* Ar = &As[t & 3][aoff];
    const u16* Br = &Bs[t & 3][boff];
    bf16x8 af[4], bv[4];
#pragma unroll
    for (int i = 0; i < 4; ++i) {
      af[i] = *(const bf16x8*)(Ar + i * 16 * 32);
      bv[i] = *(const bf16x8*)(Br + i * 16 * 32);
    }
#pragma unroll
    for (int mi = 0; mi < 4; ++mi)
#pragma unroll
      for (int ni = 0; ni < 4; ++ni)
        acc[mi][ni] = __builtin_amdgcn_mfma_f32_16x16x32_bf16(
            af[mi], bv[ni], acc[mi][ni], 0, 0, 0);
  }

  const int gr0 = m0 + wy * 64 + quad * 4;
  const int gc0 = n0 + wx * 64 + l16;
#pragma unroll
  for (int ni = 0; ni < 4; ++ni) {
    const int gc = gc0 + ni * 16;
    const float bvs = bias[gc];
#pragma unroll
    for (int mi = 0; mi < 4; ++mi) {
      const int gr = gr0 + mi * 16;
      f32x4 a = acc[mi][ni];
#pragma unroll
      for (int e = 0; e < 4; ++e) {
        float v = a[e] + bvs;
        const size_t idx = (size_t)(gr + e) * N + gc;
        if (EPI == 1) v += res[idx];
        else if (EPI == 2) v = 0.5f * v * (1.f + erff(v * 0.70710678118654752f));
        if (OBF) ((u16*)Cout)[idx] = f2bf(v);
        else     ((float*)Cout)[idx] = v;
      }
    }
  }
}

// ---------- MFMA windowed attention: one WAVE per (window, head) ----------
#define PSTR 104
__global__ __launch_bounds__(128)
void attn_mfma(const u16* __restrict__ qkv, u16* __restrict__ onat)
{
  __shared__ __bf16 Pb[2][80 * PSTR];

  const int tid  = threadIdx.x;
  const int wave = tid >> 6, lane = tid & 63;
  const int quad = lane >> 4, l16 = lane & 15;
  const int pair = blockIdx.x * 2 + wave;     // [0, 8192)
  const int nw   = pair >> 3, head = pair & 7;
  const size_t base = (size_t)nw * 77 * 768;
  const int hoff = head * 32;
  __bf16* P = Pb[wave];

  // ---- zero P cols 80..95 (NaN-safety for padded K-steps) ----
  {
    uint4 z = {0, 0, 0, 0};
    for (int r = lane; r < 80; r += 64) {
      *(uint4*)(P + r * PSTR + 80) = z;
      *(uint4*)(P + r * PSTR + 88) = z;
    }
  }

  // ---- Q, K fragments straight from global (lane l16 = token row) ----
  bf16x8 qf[5], kf[5];
  const u16* qp = qkv + base + hoff + quad * 8;
#pragma unroll
  for (int mi = 0; mi < 5; ++mi) {
    const size_t row = (size_t)(l16 + 16 * mi) * 768;
    qf[mi] = *(const bf16x8*)(qp + row);          // q block
    kf[mi] = *(const bf16x8*)(qp + row + 256);    // k block
  }

  // ---- scores S[80][80] in 25 C-tiles ----
  f32x4 s[5][5];
#pragma unroll
  for (int mi = 0; mi < 5; ++mi)
#pragma unroll
    for (int ni = 0; ni < 5; ++ni) {
      f32x4 z = {0.f, 0.f, 0.f, 0.f};
      s[mi][ni] = z;
    }
#pragma unroll
  for (int mi = 0; mi < 5; ++mi)
#pragma unroll
    for (int ni = 0; ni < 5; ++ni)
      s[mi][ni] = __builtin_amdgcn_mfma_f32_16x16x32_bf16(
          qf[mi], kf[ni], s[mi][ni], 0, 0, 0);

  // ---- V fragments (b-layout: lane l16 = d, k = quad*8+jj); k>=77 -> 0 ----
  bf16x8 vf[3][2];
  {
    const __bf16* vbb = (const __bf16*)(qkv + base + 512 + hoff + l16);
#pragma unroll
    for (int ks = 0; ks < 3; ++ks)
#pragma unroll
      for (int ni = 0; ni < 2; ++ni)
#pragma unroll
        for (int jj = 0; jj < 8; ++jj) {
          const int k = ks * 32 + quad * 8 + jj;
          vf[ks][ni][jj] = (k < 77) ? vbb[(size_t)k * 768 + 16 * ni] : (__bf16)0.f;
        }
  }

  // ---- mask cols j >= 77 (j = l16 + 16*ni; only ni==4, l16>=13) ----
  if (l16 >= 13) {
#pragma unroll
    for (int mi = 0; mi < 5; ++mi)
#pragma unroll
      for (int e = 0; e < 4; ++e) s[mi][4][e] = -1e30f;
  }

  // ---- register softmax per row (row = quad*4+e+16*mi) ----
  const float c = 0.17677669529663687f * 1.4426950408889634f;  // scale*log2(e)
  float inv[5][4];
#pragma unroll
  for (int mi = 0; mi < 5; ++mi)
#pragma unroll
    for (int e = 0; e < 4; ++e) {
      float mx = s[mi][0][e];
#pragma unroll
      for (int ni = 1; ni < 5; ++ni) mx = fmaxf(mx, s[mi][ni][e]);
#pragma unroll
      for (int off = 1; off < 16; off <<= 1) mx = fmaxf(mx, __shfl_xor(mx, off));
      float sum = 0.f;
#pragma unroll
      for (int ni = 0; ni < 5; ++ni) {
        const float ev = exp2f((s[mi][ni][e] - mx) * c);
        s[mi][ni][e] = ev;
        sum += ev;
      }
#pragma unroll
      for (int off = 1; off < 16; off <<= 1) sum += __shfl_xor(sum, off);
      inv[mi][e] = 1.f / sum;
    }

  // ---- P -> LDS (bf16), A-operand layout [m][k] ----
#pragma unroll
  for (int mi = 0; mi < 5; ++mi)
#pragma unroll
    for (int e = 0; e < 4; ++e) {
      const int m = quad * 4 + e + 16 * mi;
#pragma unroll
      for (int ni = 0; ni < 5; ++ni)
        P[m * PSTR + l16 + 16 * ni] = (__bf16)(s[mi][ni][e] * inv[mi][e]);
    }

  // ---- O = P @ V ----
  f32x4 o[5][2];
#pragma unroll
  for (int mi = 0; mi < 5; ++mi)
#pragma unroll
    for (int ni = 0; ni < 2; ++ni) {
      f32x4 z = {0.f, 0.f, 0.f, 0.f};
      o[mi][ni] = z;
    }
#pragma unroll
  for (int ks = 0; ks < 3; ++ks)
#pragma unroll
    for (int mi = 0; mi < 5; ++mi) {
      const bf16x8 af = *(const bf16x8*)(P + (l16 + 16 * mi) * PSTR + ks * 32 + quad * 8);
#pragma unroll
      for (int ni = 0; ni < 2; ++ni)
        o[mi][ni] = __builtin_amdgcn_mfma_f32_16x16x32_bf16(
            af, vf[ks][ni], o[mi][ni], 0, 0, 0);
    }

  // ---- store O, window-reversed, bf16 ----
  const int b  = nw >> 7;
  const int ih = (nw >> 4) & 7;
  const int iw = nw & 15;
#pragma unroll
  for (int mi = 0; mi < 5; ++mi)
#pragma unroll
    for (int e = 0; e < 4; ++e) {
      const int t = quad * 4 + e + 16 * mi;
      if (t < 77) {
        const int rr = t / 11, cc = t - rr * 11;
        const int y = ih * 7 + rr, xc = iw * 11 + cc;
        const size_t nat = (size_t)b * 9856 + (size_t)y * 176 + xc;
        u16* dst = onat + nat * DIM + hoff + l16;
        dst[0]  = f2bf(o[mi][0][e]);
        dst[16] = f2bf(o[mi][1][e]);
      }
    }
}

// ---------- launcher ----------
extern "C" void kernel_launch(void* const* d_in, const int* in_sizes, int n_in,
                              void* d_out, int out_size, void* d_ws, size_t ws_size,
                              hipStream_t stream)
{
  (void)in_sizes; (void)n_in; (void)out_size; (void)ws_size;
  const float* x    = (const float*)d_in[0];
  const float* g1   = (const float*)d_in[1];
  const float* b1   = (const float*)d_in[2];
  const float* wqkv = (const float*)d_in[3];
  const float* bqkv = (const float*)d_in[4];
  const float* wout = (const float*)d_in[5];
  const float* bout = (const float*)d_in[6];
  const float* g2   = (const float*)d_in[7];
  const float* b2   = (const float*)d_in[8];
  const float* w1   = (const float*)d_in[9];
  const float* bf1  = (const float*)d_in[10];
  const float* w2   = (const float*)d_in[11];
  const float* bf2  = (const float*)d_in[12];

  char* ws = (char*)d_ws;
  u16*   qkv  = (u16*)(ws);                 // M*768*2 = 121110528  (reused: h = M*512*2)
  u16*   onat = (u16*)(ws + 161480704);     // M*256*2 =  40370176
  u16*   wb   = (u16*)(ws + 201850880);     // 524288*2 = 1048576
  u16*   wqkv_b = wb;                        // image
  u16*   wout_b = wb + 196608;               // plain
  u16*   w1_b   = wb + 262144;               // image
  u16*   w2_b   = wb + 393216;               // plain
  float* x2   = (float*)d_out;              // x2 lives in d_out

  cvt_w<<<256, 256, 0, stream>>>(wqkv, wout, w1, w2, wb);
  // ln1 + qkv-proj fused (natural read, window-permuted write)
  lngemm<6, 0, 1, 1><<<1232, 256, 0, stream>>>(x, wqkv_b, g1, b1, bqkv, qkv);
  attn_mfma<<<4096, 128, 0, stream>>>(qkv, onat);
  gemm_mfma<1, 0><<<dim3(2, 616), 256, 0, stream>>>(onat, wout_b, bout, x, x2, 256, 256);
  // ln2 + fc1 + gelu fused (h reuses qkv region)
  lngemm<4, 2, 1, 0><<<1232, 256, 0, stream>>>(x2, w1_b, g2, b2, bf1, qkv);
  gemm_mfma<1, 0><<<dim3(2, 616), 256, 0, stream>>>(qkv, w2_b, bf2, x2, x2, 256, 512);
}

// Round 5
// 510.358 us; speedup vs baseline: 1.1405x; 1.1405x over previous
//
#include <hip/hip_runtime.h>
#include <hip/hip_bf16.h>

typedef unsigned short u16;
typedef unsigned int   u32;

typedef __bf16 bf16x8 __attribute__((ext_vector_type(8)));
typedef float  f32x4  __attribute__((ext_vector_type(4)));

// ---------- helpers ----------
__device__ __forceinline__ u16 f2bf(float f) {  // RNE
  u32 u = __float_as_uint(f);
  u += 0x7fffu + ((u >> 16) & 1u);
  return (u16)(u >> 16);
}
__device__ __forceinline__ u32 pack2(float a, float b) {
  return (u32)f2bf(a) | ((u32)f2bf(b) << 16);
}
__device__ __forceinline__ void gld16(const void* g, void* l) {
  __builtin_amdgcn_global_load_lds(
      (const __attribute__((address_space(1))) unsigned int*)g,
      (__attribute__((address_space(3))) unsigned int*)l, 16, 0, 0);
}

// Problem constants
#define TOK_M   78848   // B*N = 8*9856
#define DIM     256

// ---------- weight conversion: ALL matrices -> MFMA B-fragment-linear image ----
// Image: [panel][kt][nf][lane][8] (16B/lane slot), panel = 128 cols.
//   col = panel*128 + nf*16 + (lane&15), k = kt*32 + (lane>>4)*8
template<int K, int NF>
__device__ __forceinline__ void cvt_chunk(const float* __restrict__ src,
                                          u16* __restrict__ dst, int rel)
{
  constexpr int KT = K / 32;
  constexpr int PN = NF * 16;
  const int lane  = rel & 63;
  const int g     = rel >> 6;
  const int nf    = g % NF;
  const int kt    = (g / NF) % KT;
  const int panel = g / (NF * KT);
  const int col   = panel * PN + nf * 16 + (lane & 15);
  const int k0    = kt * 32 + (lane >> 4) * 8;
  const float4 a = *(const float4*)(src + (size_t)col * K + k0);
  const float4 b = *(const float4*)(src + (size_t)col * K + k0 + 4);
  uint4 o;
  o.x = pack2(a.x, a.y); o.y = pack2(a.z, a.w);
  o.z = pack2(b.x, b.y); o.w = pack2(b.z, b.w);
  *(uint4*)(dst + (size_t)rel * 8) = o;
}

__global__ __launch_bounds__(256)
void cvt_w(const float* __restrict__ wqkv, const float* __restrict__ wout,
           const float* __restrict__ w1, const float* __restrict__ w2,
           u16* __restrict__ out)
{
  const int c = blockIdx.x * 256 + threadIdx.x;   // [0, 65536) 16B chunks
  if      (c < 24576) cvt_chunk<256, 8>(wqkv, out,          c);          // qkv 768x256
  else if (c < 32768) cvt_chunk<256, 8>(wout, out + 196608, c - 24576);  // out 256x256
  else if (c < 49152) cvt_chunk<256, 8>(w1,   out + 262144, c - 32768);  // fc1 512x256
  else                cvt_chunk<512, 8>(w2,   out + 393216, c - 49152);  // fc2 256x512
}

// ---------- fused LayerNorm + qkv GEMM ----------
// Union LDS (32 KB): phase 1 uses it as At[64][256] (XOR-swizzled) for the
// LN'd A tile; after hoisting A-fragments to registers it becomes the 4x8KB
// rotating B buffers. Counted vmcnt(4) + raw s_barrier per step (loads span
// barriers). 3 blocks/CU.
template<int NPAN>
__global__ __launch_bounds__(256, 3)
void lngemm_qkv(const float* __restrict__ X, const u16* __restrict__ Wimg,
                const float* __restrict__ lg, const float* __restrict__ lb,
                const float* __restrict__ bias, u16* __restrict__ Cout)
{
  constexpr int KT = 8;
  constexpr int N  = NPAN * 128;
  constexpr int NSTEP = NPAN * KT;
  __shared__ u16 U[16384];   // 32 KB union: At[64][256] then Bs[4][4096]

  const int tid  = threadIdx.x;
  const int wave = tid >> 6, lane = tid & 63;
  const int quad = lane >> 4, l16 = lane & 15;
  const int wy = wave >> 1, wx = wave & 1;
  const int rowbase = blockIdx.x * 64;

  // ---- phase 1: LN -> LDS A-tile (all 16 row-loads in flight first) ----
  {
    const float4 gg = *(const float4*)(lg + lane * 4);
    const float4 bb = *(const float4*)(lb + lane * 4);
    const int c = lane * 4;
    float4 xv[16];
#pragma unroll
    for (int r = 0; r < 16; ++r)
      xv[r] = *(const float4*)(X + (size_t)(rowbase + wave * 16 + r) * 256 + c);
#pragma unroll
    for (int r = 0; r < 16; ++r) {
      const int row = wave * 16 + r;
      const float4 v = xv[r];
      float s = v.x + v.y + v.z + v.w;
#pragma unroll
      for (int off = 32; off; off >>= 1) s += __shfl_xor(s, off);
      const float mu = s * (1.f / 256.f);
      const float dx = v.x - mu, dy = v.y - mu, dz = v.z - mu, dw = v.w - mu;
      float q = dx * dx + dy * dy + dz * dz + dw * dw;
#pragma unroll
      for (int off = 32; off; off >>= 1) q += __shfl_xor(q, off);
      const float rstd = rsqrtf(q * (1.f / 256.f) + 1e-5f);
      uint2 o;
      o.x = pack2(dx * rstd * gg.x + bb.x, dy * rstd * gg.y + bb.y);
      o.y = pack2(dz * rstd * gg.z + bb.z, dw * rstd * gg.w + bb.w);
      *(uint2*)(U + row * 256 + (c ^ ((row & 7) * 8))) = o;
    }
  }
  __syncthreads();
  // ---- hoist A fragments to registers (At dies after this) ----
  bf16x8 af[2][8];
#pragma unroll
  for (int mi = 0; mi < 2; ++mi) {
    const int row = wy * 32 + mi * 16 + l16;
#pragma unroll
    for (int kt = 0; kt < 8; ++kt)
      af[mi][kt] = *(const bf16x8*)(U + row * 256 +
                                    ((kt * 32 + quad * 8) ^ ((row & 7) * 8)));
  }
  __syncthreads();   // all At reads done before B staging overwrites U

  // prologue: stage steps 0,1
  gld16(Wimg + tid * 8,               U + tid * 8);
  gld16(Wimg + 2048 + tid * 8,        U + 2048 + tid * 8);
  gld16(Wimg + 4096 + tid * 8,        U + 4096 + tid * 8);
  gld16(Wimg + 4096 + 2048 + tid * 8, U + 4096 + 2048 + tid * 8);

  int step = 0;
  for (int np = 0; np < NPAN; ++np) {
    f32x4 acc[2][4];
#pragma unroll
    for (int mi = 0; mi < 2; ++mi)
#pragma unroll
      for (int ni = 0; ni < 4; ++ni) {
        f32x4 z = {0.f, 0.f, 0.f, 0.f};
        acc[mi][ni] = z;
      }
#pragma unroll
    for (int kt = 0; kt < KT; ++kt, ++step) {
      {  // stage step+2 (src clamped at tail; dst rotation uniform)
        const int sn = (step + 2 < NSTEP) ? step + 2 : NSTEP - 1;
        const u16* src = Wimg + (size_t)sn * 4096;
        u16* dst = U + ((step + 2) & 3) * 4096;
        gld16(src + tid * 8,        dst + tid * 8);
        gld16(src + 2048 + tid * 8, dst + 2048 + tid * 8);
      }
      asm volatile("s_waitcnt vmcnt(4) lgkmcnt(0)" ::: "memory");
      __builtin_amdgcn_s_barrier();
      __builtin_amdgcn_sched_barrier(0);
      const u16* B0 = U + (step & 3) * 4096;
      bf16x8 bv[4];
#pragma unroll
      for (int ni = 0; ni < 4; ++ni)
        bv[ni] = *(const bf16x8*)(B0 + ((wx * 4 + ni) * 64 + lane) * 8);
#pragma unroll
      for (int mi = 0; mi < 2; ++mi)
#pragma unroll
        for (int ni = 0; ni < 4; ++ni)
          acc[mi][ni] = __builtin_amdgcn_mfma_f32_16x16x32_bf16(
              af[mi][kt], bv[ni], acc[mi][ni], 0, 0, 0);
    }
    // ---- epilogue (window-permuted rows) ----
    const int col0 = np * 128 + wx * 64 + l16;
#pragma unroll
    for (int mi = 0; mi < 2; ++mi) {
      const int r = rowbase + wy * 32 + mi * 16 + quad * 4;
#pragma unroll
      for (int e = 0; e < 4; ++e) {
        const int gr = r + e;          // natural token index
        const int b  = gr / 9856, n = gr - b * 9856;
        const int y  = n / 176,  xc = n - y * 176;
        const int ih = y / 7,    rr = y - ih * 7;
        const int iw = xc / 11,  cc = xc - iw * 11;
        const size_t orow = (size_t)(((b * 8 + ih) * 16 + iw)) * 77 + rr * 11 + cc;
#pragma unroll
        for (int ni = 0; ni < 4; ++ni) {
          const int col = col0 + ni * 16;
          Cout[orow * N + col] = f2bf(acc[mi][ni][e] + bias[col]);
        }
      }
    }
  }
}

// ---------- gemmA: A in registers, B image streamed through 32 KB LDS ----------
// Block: 64 rows, 4 waves (wave w = rows 16w..16w+15, ALL cols). A-fragments
// loaded global->VGPR once (A read exactly once per block). B staged 2 steps
// ahead, 4x8KB rotating buffers, vmcnt(4)+s_barrier per step. EPI: 1=res-add
// (f32 out), 2=gelu (bf16 out).
template<int K, int NPAN, int EPI, int OBF>
__global__ __launch_bounds__(256, 3)
void gemmA(const u16* __restrict__ A, const u16* __restrict__ Wimg,
           const float* __restrict__ bias, const float* __restrict__ res,
           void* __restrict__ Cout)
{
  constexpr int KT = K / 32;
  constexpr int N  = NPAN * 128;
  constexpr int NSTEP = NPAN * KT;
  __shared__ u16 Bs[4][4096];

  const int tid  = threadIdx.x;
  const int wave = tid >> 6, lane = tid & 63;
  const int quad = lane >> 4, l16 = lane & 15;
  const int row0 = blockIdx.x * 64 + wave * 16;

  bf16x8 af[KT];
  {
    const u16* Ap = A + (size_t)(row0 + l16) * K + quad * 8;
#pragma unroll
    for (int kt = 0; kt < KT; ++kt) af[kt] = *(const bf16x8*)(Ap + kt * 32);
  }
  gld16(Wimg + tid * 8,               Bs[0] + tid * 8);
  gld16(Wimg + 2048 + tid * 8,        Bs[0] + 2048 + tid * 8);
  gld16(Wimg + 4096 + tid * 8,        Bs[1] + tid * 8);
  gld16(Wimg + 4096 + 2048 + tid * 8, Bs[1] + 2048 + tid * 8);

  int step = 0;
  for (int np = 0; np < NPAN; ++np) {
    f32x4 acc[8];
#pragma unroll
    for (int nf = 0; nf < 8; ++nf) {
      f32x4 z = {0.f, 0.f, 0.f, 0.f};
      acc[nf] = z;
    }
#pragma unroll
    for (int kt = 0; kt < KT; ++kt, ++step) {
      {
        const int sn = (step + 2 < NSTEP) ? step + 2 : NSTEP - 1;
        const u16* src = Wimg + (size_t)sn * 4096;
        u16* dst = Bs[(step + 2) & 3];
        gld16(src + tid * 8,        dst + tid * 8);
        gld16(src + 2048 + tid * 8, dst + 2048 + tid * 8);
      }
      asm volatile("s_waitcnt vmcnt(4) lgkmcnt(0)" ::: "memory");
      __builtin_amdgcn_s_barrier();
      __builtin_amdgcn_sched_barrier(0);
      const u16* B0 = Bs[step & 3];
#pragma unroll
      for (int nf = 0; nf < 8; ++nf) {
        const bf16x8 bv = *(const bf16x8*)(B0 + (nf * 64 + lane) * 8);
        acc[nf] = __builtin_amdgcn_mfma_f32_16x16x32_bf16(
            af[kt], bv, acc[nf], 0, 0, 0);
      }
    }
    // ---- epilogue for panel np ----
#pragma unroll
    for (int nf = 0; nf < 8; ++nf) {
      const int col = np * 128 + nf * 16 + l16;
      const float bvs = bias[col];
#pragma unroll
      for (int e = 0; e < 4; ++e) {
        const int row = row0 + quad * 4 + e;
        const size_t idx = (size_t)row * N + col;
        float v = acc[nf][e] + bvs;
        if (EPI == 1) v += res[idx];
        else if (EPI == 2) v = 0.5f * v * (1.f + erff(v * 0.70710678118654752f));
        if (OBF) ((u16*)Cout)[idx] = f2bf(v);
        else     ((float*)Cout)[idx] = v;
      }
    }
  }
}

// ---------- gemmA_ln: out-proj + residual + LayerNorm2 fused ----------
// N=256, K=256. Block = 64 rows x all 256 cols -> epilogue owns full rows:
// x2 = res + o (f32, d_out) AND xn2 = LN2(x2) (bf16) computed in-register.
__global__ __launch_bounds__(256, 3)
void gemmA_ln(const u16* __restrict__ A, const u16* __restrict__ Wimg,
              const float* __restrict__ bias, const float* __restrict__ res,
              float* __restrict__ x2, const float* __restrict__ g2,
              const float* __restrict__ b2, u16* __restrict__ xn2)
{
  constexpr int NSTEP = 16;
  __shared__ u16 Bs[4][4096];

  const int tid  = threadIdx.x;
  const int wave = tid >> 6, lane = tid & 63;
  const int quad = lane >> 4, l16 = lane & 15;
  const int row0 = blockIdx.x * 64 + wave * 16;

  bf16x8 af[8];
  {
    const u16* Ap = A + (size_t)(row0 + l16) * 256 + quad * 8;
#pragma unroll
    for (int kt = 0; kt < 8; ++kt) af[kt] = *(const bf16x8*)(Ap + kt * 32);
  }
  gld16(Wimg + tid * 8,               Bs[0] + tid * 8);
  gld16(Wimg + 2048 + tid * 8,        Bs[0] + 2048 + tid * 8);
  gld16(Wimg + 4096 + tid * 8,        Bs[1] + tid * 8);
  gld16(Wimg + 4096 + 2048 + tid * 8, Bs[1] + 2048 + tid * 8);

  f32x4 acc[2][8];
#pragma unroll
  for (int np = 0; np < 2; ++np)
#pragma unroll
    for (int nf = 0; nf < 8; ++nf) {
      f32x4 z = {0.f, 0.f, 0.f, 0.f};
      acc[np][nf] = z;
    }
#pragma unroll
  for (int step = 0; step < NSTEP; ++step) {
    const int np = step >> 3, kt = step & 7;
    {
      const int sn = (step + 2 < NSTEP) ? step + 2 : NSTEP - 1;
      const u16* src = Wimg + (size_t)sn * 4096;
      u16* dst = Bs[(step + 2) & 3];
      gld16(src + tid * 8,        dst + tid * 8);
      gld16(src + 2048 + tid * 8, dst + 2048 + tid * 8);
    }
    asm volatile("s_waitcnt vmcnt(4) lgkmcnt(0)" ::: "memory");
    __builtin_amdgcn_s_barrier();
    __builtin_amdgcn_sched_barrier(0);
    const u16* B0 = Bs[step & 3];
#pragma unroll
    for (int nf = 0; nf < 8; ++nf) {
      const bf16x8 bv = *(const bf16x8*)(B0 + (nf * 64 + lane) * 8);
      acc[np][nf] = __builtin_amdgcn_mfma_f32_16x16x32_bf16(
          af[kt], bv, acc[np][nf], 0, 0, 0);
    }
  }

  // ---- epilogue: x2 = o + bias + res; LN2 -> xn2 (bf16) ----
  float gg[16], bbv[16], bsv[16];
#pragma unroll
  for (int i = 0; i < 16; ++i) {
    const int col = (i >> 3) * 128 + (i & 7) * 16 + l16;
    gg[i] = g2[col]; bbv[i] = b2[col]; bsv[i] = bias[col];
  }
#pragma unroll
  for (int e = 0; e < 4; ++e) {
    const int row = row0 + quad * 4 + e;
    const float* rp = res + (size_t)row * 256;
    float v[16];
    float s = 0.f;
#pragma unroll
    for (int i = 0; i < 16; ++i) {
      const int col = (i >> 3) * 128 + (i & 7) * 16 + l16;
      v[i] = acc[i >> 3][i & 7][e] + bsv[i] + rp[col];
      s += v[i];
    }
#pragma unroll
    for (int off = 1; off < 16; off <<= 1) s += __shfl_xor(s, off);
    const float mu = s * (1.f / 256.f);
    float q = 0.f;
#pragma unroll
    for (int i = 0; i < 16; ++i) { const float d = v[i] - mu; q += d * d; }
#pragma unroll
    for (int off = 1; off < 16; off <<= 1) q += __shfl_xor(q, off);
    const float rstd = rsqrtf(q * (1.f / 256.f) + 1e-5f);
    float* xp = x2 + (size_t)row * 256;
    u16*   yp = xn2 + (size_t)row * 256;
#pragma unroll
    for (int i = 0; i < 16; ++i) {
      const int col = (i >> 3) * 128 + (i & 7) * 16 + l16;
      xp[col] = v[i];
      yp[col] = f2bf((v[i] - mu) * rstd * gg[i] + bbv[i]);
    }
  }
}

// ---------- MFMA windowed attention: one WAVE per (window, head) ----------
#define PSTR 104
__global__ __launch_bounds__(128)
void attn_mfma(const u16* __restrict__ qkv, u16* __restrict__ onat)
{
  __shared__ __bf16 Pb[2][80 * PSTR];

  const int tid  = threadIdx.x;
  const int wave = tid >> 6, lane = tid & 63;
  const int quad = lane >> 4, l16 = lane & 15;
  const int pair = blockIdx.x * 2 + wave;     // [0, 8192)
  const int nw   = pair >> 3, head = pair & 7;
  const size_t base = (size_t)nw * 77 * 768;
  const int hoff = head * 32;
  __bf16* P = Pb[wave];

  // ---- zero P cols 80..95 (NaN-safety for padded K-steps) ----
  {
    uint4 z = {0, 0, 0, 0};
    for (int r = lane; r < 80; r += 64) {
      *(uint4*)(P + r * PSTR + 80) = z;
      *(uint4*)(P + r * PSTR + 88) = z;
    }
  }

  // ---- Q, K fragments straight from global (lane l16 = token row) ----
  bf16x8 qf[5], kf[5];
  const u16* qp = qkv + base + hoff + quad * 8;
#pragma unroll
  for (int mi = 0; mi < 5; ++mi) {
    const size_t row = (size_t)(l16 + 16 * mi) * 768;
    qf[mi] = *(const bf16x8*)(qp + row);          // q block
    kf[mi] = *(const bf16x8*)(qp + row + 256);    // k block
  }

  // ---- scores S[80][80] in 25 C-tiles ----
  f32x4 s[5][5];
#pragma unroll
  for (int mi = 0; mi < 5; ++mi)
#pragma unroll
    for (int ni = 0; ni < 5; ++ni) {
      f32x4 z = {0.f, 0.f, 0.f, 0.f};
      s[mi][ni] = z;
    }
#pragma unroll
  for (int mi = 0; mi < 5; ++mi)
#pragma unroll
    for (int ni = 0; ni < 5; ++ni)
      s[mi][ni] = __builtin_amdgcn_mfma_f32_16x16x32_bf16(
          qf[mi], kf[ni], s[mi][ni], 0, 0, 0);

  // ---- V fragments (b-layout: lane l16 = d, k = quad*8+jj); k>=77 -> 0 ----
  bf16x8 vf[3][2];
  {
    const __bf16* vbb = (const __bf16*)(qkv + base + 512 + hoff + l16);
#pragma unroll
    for (int ks = 0; ks < 3; ++ks)
#pragma unroll
      for (int ni = 0; ni < 2; ++ni)
#pragma unroll
        for (int jj = 0; jj < 8; ++jj) {
          const int k = ks * 32 + quad * 8 + jj;
          vf[ks][ni][jj] = (k < 77) ? vbb[(size_t)k * 768 + 16 * ni] : (__bf16)0.f;
        }
  }

  // ---- mask cols j >= 77 (j = l16 + 16*ni; only ni==4, l16>=13) ----
  if (l16 >= 13) {
#pragma unroll
    for (int mi = 0; mi < 5; ++mi)
#pragma unroll
      for (int e = 0; e < 4; ++e) s[mi][4][e] = -1e30f;
  }

  // ---- register softmax per row (row = quad*4+e+16*mi) ----
  const float c = 0.17677669529663687f * 1.4426950408889634f;  // scale*log2(e)
  float inv[5][4];
#pragma unroll
  for (int mi = 0; mi < 5; ++mi)
#pragma unroll
    for (int e = 0; e < 4; ++e) {
      float mx = s[mi][0][e];
#pragma unroll
      for (int ni = 1; ni < 5; ++ni) mx = fmaxf(mx, s[mi][ni][e]);
#pragma unroll
      for (int off = 1; off < 16; off <<= 1) mx = fmaxf(mx, __shfl_xor(mx, off));
      float sum = 0.f;
#pragma unroll
      for (int ni = 0; ni < 5; ++ni) {
        const float ev = exp2f((s[mi][ni][e] - mx) * c);
        s[mi][ni][e] = ev;
        sum += ev;
      }
#pragma unroll
      for (int off = 1; off < 16; off <<= 1) sum += __shfl_xor(sum, off);
      inv[mi][e] = 1.f / sum;
    }

  // ---- P -> LDS (bf16), A-operand layout [m][k] ----
#pragma unroll
  for (int mi = 0; mi < 5; ++mi)
#pragma unroll
    for (int e = 0; e < 4; ++e) {
      const int m = quad * 4 + e + 16 * mi;
#pragma unroll
      for (int ni = 0; ni < 5; ++ni)
        P[m * PSTR + l16 + 16 * ni] = (__bf16)(s[mi][ni][e] * inv[mi][e]);
    }

  // ---- O = P @ V ----
  f32x4 o[5][2];
#pragma unroll
  for (int mi = 0; mi < 5; ++mi)
#pragma unroll
    for (int ni = 0; ni < 2; ++ni) {
      f32x4 z = {0.f, 0.f, 0.f, 0.f};
      o[mi][ni] = z;
    }
#pragma unroll
  for (int ks = 0; ks < 3; ++ks)
#pragma unroll
    for (int mi = 0; mi < 5; ++mi) {
      const bf16x8 af = *(const bf16x8*)(P + (l16 + 16 * mi) * PSTR + ks * 32 + quad * 8);
#pragma unroll
      for (int ni = 0; ni < 2; ++ni)
        o[mi][ni] = __builtin_amdgcn_mfma_f32_16x16x32_bf16(
            af, vf[ks][ni], o[mi][ni], 0, 0, 0);
    }

  // ---- store O, window-reversed, bf16 ----
  const int b  = nw >> 7;
  const int ih = (nw >> 4) & 7;
  const int iw = nw & 15;
#pragma unroll
  for (int mi = 0; mi < 5; ++mi)
#pragma unroll
    for (int e = 0; e < 4; ++e) {
      const int t = quad * 4 + e + 16 * mi;
      if (t < 77) {
        const int rr = t / 11, cc = t - rr * 11;
        const int y = ih * 7 + rr, xc = iw * 11 + cc;
        const size_t nat = (size_t)b * 9856 + (size_t)y * 176 + xc;
        u16* dst = onat + nat * DIM + hoff + l16;
        dst[0]  = f2bf(o[mi][0][e]);
        dst[16] = f2bf(o[mi][1][e]);
      }
    }
}

// ---------- launcher ----------
extern "C" void kernel_launch(void* const* d_in, const int* in_sizes, int n_in,
                              void* d_out, int out_size, void* d_ws, size_t ws_size,
                              hipStream_t stream)
{
  (void)in_sizes; (void)n_in; (void)out_size; (void)ws_size;
  const float* x    = (const float*)d_in[0];
  const float* g1   = (const float*)d_in[1];
  const float* b1   = (const float*)d_in[2];
  const float* wqkv = (const float*)d_in[3];
  const float* bqkv = (const float*)d_in[4];
  const float* wout = (const float*)d_in[5];
  const float* bout = (const float*)d_in[6];
  const float* g2   = (const float*)d_in[7];
  const float* b2   = (const float*)d_in[8];
  const float* w1   = (const float*)d_in[9];
  const float* bf1  = (const float*)d_in[10];
  const float* w2   = (const float*)d_in[11];
  const float* bf2  = (const float*)d_in[12];

  char* ws = (char*)d_ws;
  u16*   qkv  = (u16*)(ws);                 // M*768*2 = 121110528 (later reused: h = M*512*2)
  u16*   xn2  = (u16*)(ws + 121110528);     // M*256*2 =  40370176
  u16*   onat = (u16*)(ws + 161480704);     // M*256*2 =  40370176
  u16*   wb   = (u16*)(ws + 201850880);     // 524288*2 = 1048576
  u16*   wqkv_b = wb;                        // image 768x256
  u16*   wout_b = wb + 196608;               // image 256x256
  u16*   w1_b   = wb + 262144;               // image 512x256
  u16*   w2_b   = wb + 393216;               // image 256x512
  u16*   h    = qkv;                         // fc1 output reuses qkv region
  float* x2   = (float*)d_out;               // x2 lives in d_out

  cvt_w<<<256, 256, 0, stream>>>(wqkv, wout, w1, w2, wb);
  lngemm_qkv<6><<<1232, 256, 0, stream>>>(x, wqkv_b, g1, b1, bqkv, qkv);
  attn_mfma<<<4096, 128, 0, stream>>>(qkv, onat);
  // out-proj + residual + LN2 fused
  gemmA_ln<<<1232, 256, 0, stream>>>(onat, wout_b, bout, x, x2, g2, b2, xn2);
  // fc1 + gelu (reads bf16 xn2)
  gemmA<256, 4, 2, 1><<<1232, 256, 0, stream>>>(xn2, w1_b, bf1, nullptr, h);
  // fc2 + residual
  gemmA<512, 2, 1, 0><<<1232, 256, 0, stream>>>(h, w2_b, bf2, x2, x2);
}